// Round 1
// baseline (449.969 us; speedup 1.0000x reference)
//
#include <hip/hip_runtime.h>
#include <cstdint>

#define NUM_USERS 50000
#define NUM_ITEMS 40000
#define EMB 64
#define NNZ_E 2000000
#define BATCH 1024
#define NCHB 125           // 40000 / 320 col blocks for k_gemm (exact)
#define SLOT_CAP 128       // edges per batch slot (E[40])
#define INF_I 0x7fffffff

typedef __attribute__((ext_vector_type(8))) short short8;   // 8 x bf16 (4 VGPRs)
typedef __attribute__((ext_vector_type(4))) float float4v;  // MFMA C/D

__device__ __forceinline__ unsigned short f2bf(float f) {
    union { float f; unsigned u; } x; x.f = f;
    unsigned r = x.u + 0x7fffu + ((x.u >> 16) & 1u);
    return (unsigned short)(r >> 16);
}
__device__ __forceinline__ float bf2f(unsigned short s) {
    return __uint_as_float(((unsigned)s) << 16);
}

// ---------------- init: map=INF; cnt/scal/compact = 0 ----------------
__global__ __launch_bounds__(256) void k_init(int* __restrict__ map, int* __restrict__ cnt,
                                              float* __restrict__ scal, int2* __restrict__ compact) {
    int t = blockIdx.x * blockDim.x + threadIdx.x;
    if (t < NUM_USERS) map[t] = INF_I;
    if (t < BATCH) cnt[t] = 0;
    if (t < 4) scal[t] = 0.f;
    if (t < BATCH * SLOT_CAP) compact[t] = make_int2(0, 0);   // zero-pad for k_hz unroll
}

__global__ void k_map(const int* __restrict__ user, int* __restrict__ map) {
    int i = blockIdx.x * blockDim.x + threadIdx.x;
    if (i < BATCH) atomicMin(&map[user[i]], i);
}

// ---------------- prep: WqT bf16 transpose | WpBf bf16 cvt ----------------
__global__ __launch_bounds__(256) void k_prep(const float* __restrict__ Wq,
                                              const float* __restrict__ Wp,
                                              unsigned short* __restrict__ WqT,
                                              unsigned short* __restrict__ WpBf) {
    __shared__ float t[128][33];
    const int bid = blockIdx.x;
    const int tid = threadIdx.x;
    if (bid < 1250) {
        const int jb = bid * 32;
        for (int idx = tid; idx < 4096; idx += 256) {
            int d = idx >> 5, c = idx & 31;
            t[d][c] = Wq[(size_t)d * NUM_ITEMS + jb + c];
        }
        __syncthreads();
        for (int idx = tid; idx < 4096; idx += 256) {
            int j = idx >> 7, d = idx & 127;
            WqT[(size_t)(jb + j) * 128 + d] = f2bf(t[d][j]);
        }
    } else {
        const int e0 = ((bid - 1250) * 256 + tid) * 4;
        float4 w = *(const float4*)&Wp[e0];
        ushort4 o;
        o.x = f2bf(w.x); o.y = f2bf(w.y); o.z = f2bf(w.z); o.w = f2bf(w.w);
        *(ushort4*)&WpBf[e0] = o;
    }
}

// ---------------- single-pass scatter into fixed-capacity slot bins ----------------
__global__ __launch_bounds__(256) void k_scatter(const int* __restrict__ rows,
                                                 const int* __restrict__ cols,
                                                 const float* __restrict__ vals,
                                                 const int* __restrict__ map,
                                                 int* __restrict__ cnt,
                                                 int2* __restrict__ compact) {
    const int e = blockIdx.x * 256 + threadIdx.x;
    if (e >= NNZ_E) return;
    int s = map[rows[e]];
    if (s == INF_I) return;
    int pos = atomicAdd(&cnt[s], 1);
    if (pos < SLOT_CAP) compact[s * SLOT_CAP + pos] = make_int2(cols[e], __float_as_int(vals[e]));
}

// ---------------- h + z + KL: 4 waves split edges, ushort2 gathers ----------------
// wave w handles edges e = w, w+4, ... (pairs via +8 stride); each lane owns 2 dims
// (ushort2 = 4B/lane, full 256B row per wave-load). LDS combine across waves.
__global__ __launch_bounds__(256) void k_hz(const int* __restrict__ user,
                                            const int* __restrict__ map,
                                            const int* __restrict__ cnt,
                                            const int2* __restrict__ compact,
                                            const unsigned short* __restrict__ WqT,
                                            const float* __restrict__ bq,
                                            const float* __restrict__ eps,
                                            unsigned short* __restrict__ zbBf,
                                            float* __restrict__ zF32,
                                            float* __restrict__ scal) {
    __shared__ float sh[4][128];
    const int i = blockIdx.x;
    const int tid = threadIdx.x;
    const int w = tid >> 6, lane = tid & 63;
    const int u = user[i];
    const int s = map[u];
    const int n8 = (min(cnt[s], SLOT_CAP) + 7) & ~7;   // compact zero-padded -> safe
    const int2* cp = compact + s * SLOT_CAP;
    float ax = 0.f, ay = 0.f;
    for (int e = w; e < n8; e += 8) {
        int2 c0 = cp[e], c1 = cp[e + 4];
        ushort2 w0 = *(const ushort2*)&WqT[(size_t)c0.x * 128 + lane * 2];
        ushort2 w1 = *(const ushort2*)&WqT[(size_t)c1.x * 128 + lane * 2];
        float v0 = __int_as_float(c0.y), v1 = __int_as_float(c1.y);
        ax = fmaf(v0, bf2f(w0.x), ax);
        ay = fmaf(v0, bf2f(w0.y), ay);
        ax = fmaf(v1, bf2f(w1.x), ax);
        ay = fmaf(v1, bf2f(w1.y), ay);
    }
    sh[w][lane * 2] = ax;
    sh[w][lane * 2 + 1] = ay;
    __syncthreads();
    float h = 0.f;
    if (tid < 128) h = sh[0][tid] + sh[1][tid] + sh[2][tid] + sh[3][tid] + bq[tid];
    __syncthreads();
    if (tid < 128) sh[0][tid] = h;
    __syncthreads();
    if (tid < 64) {
        float mu = sh[0][tid];
        float lv = sh[0][tid + 64];
        float z = fmaf(eps[(size_t)u * EMB + tid], __expf(0.5f * lv), mu);
        zbBf[i * EMB + tid] = f2bf(z);
        zF32[i * EMB + tid] = z;
        float kl = 1.0f + lv - mu * mu - __expf(lv);
        #pragma unroll
        for (int o = 32; o; o >>= 1) kl += __shfl_down(kl, o);
        if (tid == 0) atomicAdd(&scal[1], kl);
    }
}

// ---------------- x pass: per batch row, stream x (float4, full BW) ----------------
// Exploits x sparsity (~2%): sum_j x_ij*v_ij = z_i . (sum_j x_ij Wp_j) + sum_j x_ij bp_j.
// Ballot nonzeros per 64-lane float4 chunk; per nonzero j, all 64 lanes add one
// fp32 Wp row (256B coalesced), lane owning dim=lane. Removes x from k_gemm.
__global__ __launch_bounds__(256) void k_xpass(const float* __restrict__ x,
                                               const float* __restrict__ Wp,
                                               const float* __restrict__ bp,
                                               float* __restrict__ xWp,
                                               float2* __restrict__ rowAux) {
    __shared__ float sacc[4][EMB];
    __shared__ float sscal[4][2];
    const int row = blockIdx.x;
    const int tid = threadIdx.x;
    const int w = tid >> 6, lane = tid & 63;
    const float4* xr = (const float4*)(x + (size_t)row * NUM_ITEMS);
    float acc = 0.f, sx = 0.f, xb = 0.f;
    // float4 index space: 40000/4 = 10000; idx4 = k*256 + w*64 + lane
    for (int k = 0; k < 40; k++) {
        const int idx4 = k * 256 + (w << 6) + lane;
        float4 xv = make_float4(0.f, 0.f, 0.f, 0.f);
        if (idx4 < 10000) xv = xr[idx4];
        #pragma unroll
        for (int q = 0; q < 4; q++) {
            float v = (q == 0) ? xv.x : (q == 1) ? xv.y : (q == 2) ? xv.z : xv.w;
            unsigned long long b = __ballot(v != 0.f);
            while (b) {                       // wave-uniform loop
                const int sbit = __ffsll((long long)b) - 1;
                b &= b - 1;
                const float xs = __shfl(v, sbit);
                const int j = ((k * 256 + (w << 6) + sbit) << 2) + q;
                acc = fmaf(xs, Wp[(size_t)j * EMB + lane], acc);
                sx += xs;                     // replicated across lanes (same value)
                xb = fmaf(xs, bp[j], xb);
            }
        }
    }
    sacc[w][lane] = acc;
    if (lane == 0) { sscal[w][0] = sx; sscal[w][1] = xb; }
    __syncthreads();
    if (tid < EMB)
        xWp[(size_t)row * EMB + tid] = sacc[0][tid] + sacc[1][tid] + sacc[2][tid] + sacc[3][tid];
    if (tid == 0)
        rowAux[row] = make_float2(sscal[0][0] + sscal[1][0] + sscal[2][0] + sscal[3][0],
                                  sscal[0][1] + sscal[1][1] + sscal[2][1] + sscal[3][1]);
}

// ---------------- MFMA GEMM: pure LSE (no x) -> per-block (m, s) partials ----------------
// grid (125, 8); 256 thr = 4 waves; wave: 32 rows x 320 cols (5 chunks of 64)
__global__ __launch_bounds__(256) void k_gemm(const unsigned short* __restrict__ zbBf,
                                              const unsigned short* __restrict__ WpBf,
                                              const float* __restrict__ bp,
                                              float2* __restrict__ part) {
    const int tid = threadIdx.x;
    const int wid = tid >> 6, lane = tid & 63;
    const int l15 = lane & 15, quad = lane >> 4;
    const int ibase = blockIdx.y * 128 + wid * 32;

    short8 af[2][2];
    #pragma unroll
    for (int mt = 0; mt < 2; mt++) {
        const unsigned short* pa = zbBf + (size_t)(ibase + mt * 16 + l15) * EMB + quad * 8;
        af[mt][0] = *(const short8*)pa;
        af[mt][1] = *(const short8*)(pa + 32);
    }

    float m_run[2][4], s_run[2][4];
    #pragma unroll
    for (int mt = 0; mt < 2; mt++)
        #pragma unroll
        for (int r = 0; r < 4; r++) { m_run[mt][r] = -1e30f; s_run[mt][r] = 0.f; }

    #pragma unroll
    for (int c5 = 0; c5 < 5; c5++) {
        const int jb = blockIdx.x * 320 + c5 * 64;
        short8 bfr[4][2];
        #pragma unroll
        for (int nt = 0; nt < 4; nt++) {
            const unsigned short* pb = WpBf + (size_t)(jb + nt * 16 + l15) * EMB + quad * 8;
            bfr[nt][0] = *(const short8*)pb;
            bfr[nt][1] = *(const short8*)(pb + 32);
        }
        float4v acc[2][4];
        #pragma unroll
        for (int mt = 0; mt < 2; mt++)
            #pragma unroll
            for (int nt = 0; nt < 4; nt++)
                acc[mt][nt] = (float4v){0.f, 0.f, 0.f, 0.f};
        #pragma unroll
        for (int kh = 0; kh < 2; kh++)
            #pragma unroll
            for (int mt = 0; mt < 2; mt++)
                #pragma unroll
                for (int nt = 0; nt < 4; nt++)
                    acc[mt][nt] = __builtin_amdgcn_mfma_f32_16x16x32_bf16(
                        af[mt][kh], bfr[nt][kh], acc[mt][nt], 0, 0, 0);
        float bpv[4];
        #pragma unroll
        for (int nt = 0; nt < 4; nt++) bpv[nt] = bp[jb + nt * 16 + l15];
        #pragma unroll
        for (int mt = 0; mt < 2; mt++) {
            #pragma unroll
            for (int r = 0; r < 4; r++) {
                float v0 = acc[mt][0][r] + bpv[0];
                float v1 = acc[mt][1][r] + bpv[1];
                float v2 = acc[mt][2][r] + bpv[2];
                float v3 = acc[mt][3][r] + bpv[3];
                float mx = fmaxf(fmaxf(v0, v1), fmaxf(v2, v3));
                float M2 = fmaxf(m_run[mt][r], mx);
                float ls = __expf(v0 - M2) + __expf(v1 - M2) +
                           __expf(v2 - M2) + __expf(v3 - M2);
                s_run[mt][r] = s_run[mt][r] * __expf(m_run[mt][r] - M2) + ls;
                m_run[mt][r] = M2;
            }
        }
    }
    // reduce across the 16 l15 lanes (same rows)
    #pragma unroll
    for (int d = 1; d < 16; d <<= 1) {
        #pragma unroll
        for (int mt = 0; mt < 2; mt++)
            #pragma unroll
            for (int r = 0; r < 4; r++) {
                float m2 = __shfl_xor(m_run[mt][r], d);
                float s2 = __shfl_xor(s_run[mt][r], d);
                float M = fmaxf(m_run[mt][r], m2);
                s_run[mt][r] = s_run[mt][r] * __expf(m_run[mt][r] - M)
                             + s2 * __expf(m2 - M);
                m_run[mt][r] = M;
            }
    }
    if (l15 == 0) {
        #pragma unroll
        for (int mt = 0; mt < 2; mt++)
            #pragma unroll
            for (int r = 0; r < 4; r++) {
                const int gi = ibase + mt * 16 + quad * 4 + r;
                part[(size_t)gi * NCHB + blockIdx.x] =
                    make_float2(m_run[mt][r], s_run[mt][r]);
            }
    }
}

// ---------------- merge: lse per row + z.xWp dot + loss ----------------
__global__ __launch_bounds__(64) void k_merge(const float2* __restrict__ part,
                                              const float* __restrict__ zF32,
                                              const float* __restrict__ xWp,
                                              const float2* __restrict__ rowAux,
                                              float* __restrict__ scal) {
    const int row = blockIdx.x;
    const int lane = threadIdx.x;
    float M = -1e30f, S = 0.f;
    for (int c = lane; c < NCHB; c += 64) {
        float2 p = part[(size_t)row * NCHB + c];
        float M2 = fmaxf(M, p.x);
        S = S * __expf(M - M2) + p.y * __expf(p.x - M2);
        M = M2;
    }
    float d = zF32[(size_t)row * EMB + lane] * xWp[(size_t)row * EMB + lane];
    #pragma unroll
    for (int o = 1; o < 64; o <<= 1) {
        float M2 = __shfl_xor(M, o);
        float S2 = __shfl_xor(S, o);
        float Mn = fmaxf(M, M2);
        S = S * __expf(M - Mn) + S2 * __expf(M2 - Mn);
        M = Mn;
        d += __shfl_xor(d, o);
    }
    if (lane == 0) {
        float2 aux = rowAux[row];
        float lse = M + logf(S);
        float loss = d + aux.y - lse * aux.x;
        atomicAdd(&scal[0], loss);
    }
}

__global__ void k_final(const float* __restrict__ scal, float* __restrict__ out) {
    if (threadIdx.x == 0 && blockIdx.x == 0) {
        out[0] = -scal[0] * (1.0f / BATCH);
        out[1] = -0.5f * scal[1] * (1.0f / BATCH);
    }
}

extern "C" void kernel_launch(void* const* d_in, const int* in_sizes, int n_in,
                              void* d_out, int out_size, void* d_ws, size_t ws_size,
                              hipStream_t stream) {
    const float* graph_vals = (const float*)d_in[0];
    const float* Wq         = (const float*)d_in[1];
    const float* bq         = (const float*)d_in[2];
    const float* Wp         = (const float*)d_in[3];
    const float* bp         = (const float*)d_in[4];
    const float* x          = (const float*)d_in[5];
    const float* eps        = (const float*)d_in[6];
    const int*   graph_rows = (const int*)d_in[7];
    const int*   graph_cols = (const int*)d_in[8];
    const int*   user       = (const int*)d_in[9];
    float* out = (float*)d_out;

    char* ws = (char*)d_ws;
    int*            map     = (int*)(ws + 0);                    //   200,704
    int*            cnt     = (int*)(ws + 200704);               //     4,096
    float*          scal    = (float*)(ws + 204800);             //       256
    int2*           compact = (int2*)(ws + 205056);              // 1,048,576 -> 1,253,632
    unsigned short* zbBf    = (unsigned short*)(ws + 1253632);   //   131,072 -> 1,384,704
    float*          zF32    = (float*)(ws + 1384704);            //   262,144 -> 1,646,848
    float*          xWp     = (float*)(ws + 1646848);            //   262,144 -> 1,908,992
    float2*         rowAux  = (float2*)(ws + 1908992);           //     8,192 -> 1,917,184
    float2*         part    = (float2*)(ws + 1917184);           // 1,024,000 -> 2,941,184
    unsigned short* WpBf    = (unsigned short*)(ws + 2941184);   // 5,120,000 -> 8,061,184
    unsigned short* WqT     = (unsigned short*)(ws + 8061184);   // 10,240,000 -> 18,301,184

    k_init<<<512, 256, 0, stream>>>(map, cnt, scal, compact);
    k_map<<<4, 256, 0, stream>>>(user, map);
    k_prep<<<3750, 256, 0, stream>>>(Wq, Wp, WqT, WpBf);
    k_scatter<<<7813, 256, 0, stream>>>(graph_rows, graph_cols, graph_vals, map, cnt, compact);
    k_hz<<<BATCH, 256, 0, stream>>>(user, map, cnt, compact, WqT, bq, eps, zbBf, zF32, scal);
    k_xpass<<<BATCH, 256, 0, stream>>>(x, Wp, bp, xWp, rowAux);
    dim3 g(NCHB, BATCH / 128);
    k_gemm<<<g, 256, 0, stream>>>(zbBf, WpBf, bp, part);
    k_merge<<<BATCH, 64, 0, stream>>>(part, zF32, xWp, rowAux, scal);
    k_final<<<1, 64, 0, stream>>>(scal, out);
}